// Round 1
// baseline (519.242 us; speedup 1.0000x reference)
//
#include <hip/hip_runtime.h>

typedef unsigned short u16;
typedef unsigned int   u32;
typedef float  f32x4  __attribute__((ext_vector_type(4)));
typedef __bf16 bf16x8 __attribute__((ext_vector_type(8)));
typedef u16    u16x8  __attribute__((ext_vector_type(8)));
typedef u32    u32x4  __attribute__((ext_vector_type(4)));
typedef u32    u32x2  __attribute__((ext_vector_type(2)));

#define DEVINL static __device__ __forceinline__

constexpr int BB = 8, CC = 256, DD = 32, NN = 4096;
constexpr float L2E = 1.4426950408889634f;

DEVINL f32x4 mfma16(u16x8 a, u16x8 b, f32x4 c) {
  return __builtin_amdgcn_mfma_f32_16x16x32_bf16(
      __builtin_bit_cast(bf16x8, a), __builtin_bit_cast(bf16x8, b), c, 0, 0, 0);
}

DEVINL u32 pk_bf16(float lo, float hi) {
  u32 r;
  asm("v_cvt_pk_bf16_f32 %0, %1, %2" : "=v"(r) : "v"(lo), "v"(hi));
  return r;
}

DEVINL float exp2fast(float x) { return __builtin_amdgcn_exp2f(x); }

// ---------------------------------------------------------------------------
// Kernel 1: 1x1-conv projections. Produces bf16 qT[b][n][32], kT[b][m][32],
// v[b][c][n].  Block = (b, 64-column tile), 256 threads, input tile in LDS.
// ---------------------------------------------------------------------------
__global__ __launch_bounds__(256) void proj_kernel(
    const float* __restrict__ in,
    const float* __restrict__ wq, const float* __restrict__ bq,
    const float* __restrict__ wk, const float* __restrict__ bk,
    const float* __restrict__ wv, const float* __restrict__ bv,
    u16* __restrict__ qT, u16* __restrict__ kT, u16* __restrict__ vbf) {
  __shared__ float sin_[256][64];
  const int b   = blockIdx.y;
  const int n0  = blockIdx.x * 64;
  const int t   = threadIdx.x;
  const int col = t & 63;
  const int grp = t >> 6;            // wave id, uniform per wave

  const float* inb = in + (size_t)b * CC * NN;
#pragma unroll 4
  for (int j = 0; j < 64; ++j) {
    const int c = grp * 64 + j;
    sin_[c][col] = inb[(size_t)c * NN + n0 + col];
  }
  __syncthreads();

  // q / k: wave 0 -> q[0:16], wave 1 -> q[16:32], wave 2 -> k[0:16], wave 3 -> k[16:32]
  {
    const float* wgt  = (grp < 2) ? wq : wk;
    const float* bias = (grp < 2) ? bq : bk;
    u16* outT         = (grp < 2) ? qT : kT;
    const int d0 = (grp & 1) * 16;
    float acc[16];
#pragma unroll
    for (int j = 0; j < 16; ++j) acc[j] = bias[d0 + j];
#pragma unroll 4
    for (int c = 0; c < 256; ++c) {
      const float x = sin_[c][col];
#pragma unroll
      for (int j = 0; j < 16; ++j) acc[j] += wgt[(d0 + j) * 256 + c] * x;
    }
    u32x4 lo, hi;
    lo.x = pk_bf16(acc[0],  acc[1]);  lo.y = pk_bf16(acc[2],  acc[3]);
    lo.z = pk_bf16(acc[4],  acc[5]);  lo.w = pk_bf16(acc[6],  acc[7]);
    hi.x = pk_bf16(acc[8],  acc[9]);  hi.y = pk_bf16(acc[10], acc[11]);
    hi.z = pk_bf16(acc[12], acc[13]); hi.w = pk_bf16(acc[14], acc[15]);
    u32x4* dst = (u32x4*)(outT + ((size_t)(b * NN + n0 + col)) * DD + d0);
    dst[0] = lo; dst[1] = hi;
  }

  // v: wave w -> channels [64w, 64w+64) in chunks of 8
#pragma unroll 1
  for (int ch = 0; ch < 8; ++ch) {
    const int o0 = grp * 64 + ch * 8;
    float acc[8];
#pragma unroll
    for (int j = 0; j < 8; ++j) acc[j] = bv[o0 + j];
#pragma unroll 4
    for (int c = 0; c < 256; ++c) {
      const float x = sin_[c][col];
#pragma unroll
      for (int j = 0; j < 8; ++j) acc[j] += wv[(o0 + j) * 256 + c] * x;
    }
#pragma unroll
    for (int j = 0; j < 8; ++j)
      vbf[((size_t)(b * CC + o0 + j)) * NN + n0 + col] = (u16)(pk_bf16(acc[j], 0.f) & 0xffffu);
  }
}

// ---------------------------------------------------------------------------
// Kernel 2: per-column softmax statistics M[b][m] = max_i S, invL = 1/sum exp.
// One wave per 16-column strip; kT B-frag in regs; 256 MFMAs over i.
// ---------------------------------------------------------------------------
__global__ __launch_bounds__(256) void rowstat_kernel(
    const u16* __restrict__ qT, const u16* __restrict__ kT,
    float* __restrict__ Mx, float* __restrict__ invL) {
  const int lane = threadIdx.x & 63;
  const int wave = threadIdx.x >> 6;
  const int strip = blockIdx.x * 4 + wave;       // 2048 strips = 8 b * 256
  const int b  = strip >> 8;
  const int m0 = (strip & 255) * 16;
  const int r = lane & 15, g = lane >> 4;

  const u16x8 kB = *(const u16x8*)(kT + ((size_t)(b * NN + m0 + r)) * DD + 8 * g);
  const u16* qbase = qT + ((size_t)(b * NN + r)) * DD + 8 * g;

  float vmax = -3.0e38f, vsum = 0.f;
  for (int it = 0; it < 256; ++it) {
    const u16x8 qA = *(const u16x8*)(qbase + (size_t)it * 16 * DD);
    f32x4 s = mfma16(qA, kB, f32x4{0.f, 0.f, 0.f, 0.f});
    const float sm = fmaxf(fmaxf(s.x, s.y), fmaxf(s.z, s.w));
    const float nm = fmaxf(vmax, sm);
    vsum = vsum * exp2fast((vmax - nm) * L2E)
         + exp2fast((s.x - nm) * L2E) + exp2fast((s.y - nm) * L2E)
         + exp2fast((s.z - nm) * L2E) + exp2fast((s.w - nm) * L2E);
    vmax = nm;
  }
#pragma unroll
  for (int off = 16; off < 64; off <<= 1) {
    const float om = __shfl_xor(vmax, off);
    const float os = __shfl_xor(vsum, off);
    const float nm = fmaxf(vmax, om);
    vsum = vsum * exp2fast((vmax - nm) * L2E) + os * exp2fast((om - nm) * L2E);
    vmax = nm;
  }
  if (lane < 16) {
    Mx[b * NN + m0 + lane]   = vmax;
    invL[b * NN + m0 + lane] = 1.0f / vsum;
  }
}

// ---------------------------------------------------------------------------
// Kernel 3: attention + epilogue.  256 blocks x 512 threads (8 waves).
// Wave owns c-strip (32 chans, shared by block) x m-tile (128 cols).
// Per 32-i step: S = MFMA(qA, kB); P = exp2 in-register; C-frag -> B-frag via
// cvt_pk (k-permutation-consistent); O += MFMA(vA, P).  q/v staged in LDS.
// ---------------------------------------------------------------------------
__global__ __launch_bounds__(512, 2) void attn_kernel(
    const u16* __restrict__ qT, const u16* __restrict__ kT, const u16* __restrict__ vv,
    const float* __restrict__ Mx, const float* __restrict__ invL,
    const float* __restrict__ inp, const float* __restrict__ gptr,
    float* __restrict__ out) {
  __shared__ u32 q_lds[32 * 20];   // rows of 80B (16 data dwords + pad) -> b128-clean
  __shared__ u32 v_lds[32 * 20];

  const int tid  = threadIdx.x;
  const int lane = tid & 63;
  const int wave = tid >> 6;                 // 0..7
  const int r = lane & 15, g = lane >> 4;

  const int bi   = blockIdx.x >> 5;          // 8 batches
  const int rest = blockIdx.x & 31;
  const int cs   = rest >> 2;                // 0..7  c-strip
  const int mg   = rest & 3;                 // 0..3  m-group
  const int m0   = (mg * 8 + wave) * 128;
  const int c0   = cs * 32;
  const float gamma = gptr[0];

  // preload kT B-frags for this wave's 128 columns
  u16x8 kB[8];
#pragma unroll
  for (int t = 0; t < 8; ++t)
    kB[t] = *(const u16x8*)(kT + ((size_t)(bi * NN + m0 + t * 16 + r)) * DD + 8 * g);
  float msc[8];
#pragma unroll
  for (int t = 0; t < 8; ++t) msc[t] = Mx[bi * NN + m0 + t * 16 + r] * L2E;

  f32x4 acc[2][8];
#pragma unroll
  for (int cb = 0; cb < 2; ++cb)
#pragma unroll
    for (int t = 0; t < 8; ++t) acc[cb][t] = f32x4{0.f, 0.f, 0.f, 0.f};

  // staging: each of 512 threads moves 1 dword of q-tile and 1 of v-tile
  const int srow = tid >> 4;   // 0..31
  const int sdw  = tid & 15;   // dword within row
  const u32* qsrc = (const u32*)(qT + ((size_t)(bi * NN + srow)) * DD) + sdw;
  const u32* vsrc = (const u32*)(vv + ((size_t)(bi * CC + c0 + srow)) * NN) + sdw;
  u32* qdst = q_lds + srow * 20 + sdw;
  u32* vdst = v_lds + srow * 20 + sdw;

  qdst[0] = qsrc[0];
  vdst[0] = vsrc[0];

  for (int i0 = 0; i0 < NN; i0 += 32) {
    __syncthreads();                          // staged tile visible
    const bool more = (i0 + 32) < NN;
    u32 nq = 0, nv = 0;
    if (more) {                               // issue next-tile loads early (latency under compute)
      nq = qsrc[(size_t)(i0 + 32) * (DD / 2)];
      nv = vsrc[(i0 + 32) >> 1];
    }

    const u16x8 qA0 = __builtin_bit_cast(u16x8, *(const u32x4*)(q_lds + r * 20 + 4 * g));
    const u16x8 qA1 = __builtin_bit_cast(u16x8, *(const u32x4*)(q_lds + (16 + r) * 20 + 4 * g));
    const u32x2 vl0 = *(const u32x2*)(v_lds + r * 20 + 2 * g);
    const u32x2 vh0 = *(const u32x2*)(v_lds + r * 20 + 2 * g + 8);
    const u32x2 vl1 = *(const u32x2*)(v_lds + (16 + r) * 20 + 2 * g);
    const u32x2 vh1 = *(const u32x2*)(v_lds + (16 + r) * 20 + 2 * g + 8);
    const u16x8 vA0 = __builtin_bit_cast(u16x8, u32x4{vl0.x, vl0.y, vh0.x, vh0.y});
    const u16x8 vA1 = __builtin_bit_cast(u16x8, u32x4{vl1.x, vl1.y, vh1.x, vh1.y});

#pragma unroll
    for (int t = 0; t < 8; ++t) {
      const f32x4 s0 = mfma16(qA0, kB[t], f32x4{0.f, 0.f, 0.f, 0.f});
      const f32x4 s1 = mfma16(qA1, kB[t], f32x4{0.f, 0.f, 0.f, 0.f});
      const float p0 = exp2fast(fmaf(s0.x, L2E, -msc[t]));
      const float p1 = exp2fast(fmaf(s0.y, L2E, -msc[t]));
      const float p2 = exp2fast(fmaf(s0.z, L2E, -msc[t]));
      const float p3 = exp2fast(fmaf(s0.w, L2E, -msc[t]));
      const float p4 = exp2fast(fmaf(s1.x, L2E, -msc[t]));
      const float p5 = exp2fast(fmaf(s1.y, L2E, -msc[t]));
      const float p6 = exp2fast(fmaf(s1.z, L2E, -msc[t]));
      const float p7 = exp2fast(fmaf(s1.w, L2E, -msc[t]));
      const u32x4 pb = {pk_bf16(p0, p1), pk_bf16(p2, p3), pk_bf16(p4, p5), pk_bf16(p6, p7)};
      const u16x8 PB = __builtin_bit_cast(u16x8, pb);
      acc[0][t] = mfma16(vA0, PB, acc[0][t]);
      acc[1][t] = mfma16(vA1, PB, acc[1][t]);
    }
    __syncthreads();                          // all reads done before overwrite
    if (more) { qdst[0] = nq; vdst[0] = nv; }
  }

  // epilogue: out = gamma * O * invL + input
#pragma unroll
  for (int t = 0; t < 8; ++t) {
    const float il = invL[bi * NN + m0 + t * 16 + r] * gamma;
#pragma unroll
    for (int cb = 0; cb < 2; ++cb) {
#pragma unroll
      for (int rr = 0; rr < 4; ++rr) {
        const int c = c0 + cb * 16 + g * 4 + rr;
        const size_t idx = ((size_t)(bi * CC + c)) * NN + m0 + t * 16 + r;
        out[idx] = acc[cb][t][rr] * il + inp[idx];
      }
    }
  }
}

// ---------------------------------------------------------------------------
extern "C" void kernel_launch(void* const* d_in, const int* in_sizes, int n_in,
                              void* d_out, int out_size, void* d_ws, size_t ws_size,
                              hipStream_t stream) {
  const float* in  = (const float*)d_in[0];
  const float* wq  = (const float*)d_in[1];
  const float* bq  = (const float*)d_in[2];
  const float* wk  = (const float*)d_in[3];
  const float* bk  = (const float*)d_in[4];
  const float* wv  = (const float*)d_in[5];
  const float* bv  = (const float*)d_in[6];
  const float* gam = (const float*)d_in[7];
  float* out = (float*)d_out;

  char* ws = (char*)d_ws;
  u16* qT  = (u16*)(ws);                         // 2 MB
  u16* kT  = (u16*)(ws + (2u << 20));            // 2 MB
  u16* vbf = (u16*)(ws + (4u << 20));            // 16 MB
  float* Mx = (float*)(ws + (20u << 20));        // 128 KB
  float* iL = (float*)(ws + (20u << 20) + (1u << 17)); // 128 KB

  proj_kernel<<<dim3(64, 8), 256, 0, stream>>>(in, wq, bq, wk, bk, wv, bv, qT, kT, vbf);
  rowstat_kernel<<<512, 256, 0, stream>>>(qT, kT, Mx, iL);
  attn_kernel<<<256, 512, 0, stream>>>(qT, kT, vbf, Mx, iL, in, gam, out);
}

// Round 5
// 261.998 us; speedup vs baseline: 1.9819x; 1.9819x over previous
//
#include <hip/hip_runtime.h>

typedef unsigned short u16;
typedef unsigned int   u32;
typedef float  f32x4  __attribute__((ext_vector_type(4)));
typedef __bf16 bf16x8 __attribute__((ext_vector_type(8)));
typedef u16    u16x8  __attribute__((ext_vector_type(8)));
typedef u32    u32x4  __attribute__((ext_vector_type(4)));
typedef u32    u32x2  __attribute__((ext_vector_type(2)));

#define DEVINL static __device__ __forceinline__

constexpr int CC = 256, DD = 32, NN = 4096;
constexpr float L2E = 1.4426950408889634f;

DEVINL f32x4 mfma16(u16x8 a, u16x8 b, f32x4 c) {
  return __builtin_amdgcn_mfma_f32_16x16x32_bf16(
      __builtin_bit_cast(bf16x8, a), __builtin_bit_cast(bf16x8, b), c, 0, 0, 0);
}

DEVINL u32 pk_bf16(float lo, float hi) {
  u32 r;
  asm("v_cvt_pk_bf16_f32 %0, %1, %2" : "=v"(r) : "v"(lo), "v"(hi));
  return r;
}

DEVINL float exp2fast(float x) { return __builtin_amdgcn_exp2f(x); }

// ---------------------------------------------------------------------------
// Kernel 1: projections as MFMA GEMM — SELF-CONTAINED (no wcvt, no Wb ws).
// Block = (b, 64-col tile), 256 threads (4 waves).  x tile staged transposed
// bf16 in LDS; weights loaded per-k-step straight from fp32 wq/wk/wv (L2-hot)
// and converted to bf16 fragments in-register.  Wave w owns stacked output
// rows [80w, 80w+80) (0-255 = v, 256-287 = q, 288-319 = k).
// ---------------------------------------------------------------------------
__global__ __launch_bounds__(256, 2) void proj_kernel(
    const float* __restrict__ in,
    const float* __restrict__ wq, const float* __restrict__ wk,
    const float* __restrict__ wv,
    const float* __restrict__ bq, const float* __restrict__ bk,
    const float* __restrict__ bv,
    u16* __restrict__ qT, u16* __restrict__ kT, u16* __restrict__ vbf) {
  __shared__ u16 xT[64 * 264];   // [n][c] bf16, rows 528B (512 data + 16 pad)
  const int t  = threadIdx.x;
  const int b  = blockIdx.x & 7;
  const int n0 = (blockIdx.x >> 3) * 64;

  {  // stage x tile -> transposed bf16 LDS
    const int n = t & 63;
    const int cg0 = t >> 6;
    const float* src = in + (size_t)b * 256 * NN + n0 + n;
#pragma unroll
    for (int pass = 0; pass < 8; ++pass) {
      const int cg = cg0 + pass * 4;
      float x[8];
#pragma unroll
      for (int j = 0; j < 8; ++j) x[j] = src[(size_t)(cg * 8 + j) * NN];
      u32x4 p;
      p.x = pk_bf16(x[0], x[1]); p.y = pk_bf16(x[2], x[3]);
      p.z = pk_bf16(x[4], x[5]); p.w = pk_bf16(x[6], x[7]);
      *(u32x4*)(&xT[n * 264 + cg * 8]) = p;
    }
  }
  __syncthreads();

  const int lane = t & 63, w = t >> 6;
  const int r = lane & 15, g = lane >> 4;
  const int o0 = w * 80;

  // per-lane weight-row pointers for the 5 output sub-tiles
  const float* wsrc[5];
#pragma unroll
  for (int ot = 0; ot < 5; ++ot) {
    const int o = o0 + ot * 16 + r;           // stacked output row
    wsrc[ot] = (o < 256) ? wv + (size_t)o * 256
             : (o < 288) ? wq + (size_t)(o - 256) * 256
                         : wk + (size_t)(o - 288) * 256;
  }

  f32x4 acc[5][4];
#pragma unroll
  for (int ot = 0; ot < 5; ++ot)
#pragma unroll
    for (int nt = 0; nt < 4; ++nt) acc[ot][nt] = f32x4{0.f, 0.f, 0.f, 0.f};

#pragma unroll
  for (int k = 0; k < 8; ++k) {
    u16x8 a[5], bfr[4];
#pragma unroll
    for (int ot = 0; ot < 5; ++ot) {
      const f32x4 w0 = *(const f32x4*)(wsrc[ot] + k * 32 + 8 * g);
      const f32x4 w1 = *(const f32x4*)(wsrc[ot] + k * 32 + 8 * g + 4);
      const u32x4 pw = {pk_bf16(w0.x, w0.y), pk_bf16(w0.z, w0.w),
                        pk_bf16(w1.x, w1.y), pk_bf16(w1.z, w1.w)};
      a[ot] = __builtin_bit_cast(u16x8, pw);
    }
#pragma unroll
    for (int nt = 0; nt < 4; ++nt)
      bfr[nt] = *(const u16x8*)(&xT[(r + 16 * nt) * 264 + k * 32 + g * 8]);
#pragma unroll
    for (int ot = 0; ot < 5; ++ot)
#pragma unroll
      for (int nt = 0; nt < 4; ++nt)
        acc[ot][nt] = mfma16(a[ot], bfr[nt], acc[ot][nt]);
  }

  // epilogue: bias + store (v rows -> vbf[c][n]; q/k rows -> packed qT/kT[n][d])
#pragma unroll
  for (int ot = 0; ot < 5; ++ot) {
    const int ob = o0 + ot * 16;
    if (ob < 256) {
      const f32x4 bs = *(const f32x4*)(bv + ob + 4 * g);
#pragma unroll
      for (int nt = 0; nt < 4; ++nt)
#pragma unroll
        for (int j = 0; j < 4; ++j) {
          const float vvv = acc[ot][nt][j] + bs[j];
          vbf[(size_t)(b * 256 + ob + 4 * g + j) * NN + n0 + r + 16 * nt] =
              (u16)(pk_bf16(vvv, 0.f) & 0xffffu);
        }
    } else {
      u16* dst;
      const float* bsrc;
      if (ob < 288) { dst = qT; bsrc = bq + (ob - 256); }
      else          { dst = kT; bsrc = bk + (ob - 288); }
      const f32x4 bs = *(const f32x4*)(bsrc + 4 * g);
      const int d0 = ((ob - 256) & 31) + 4 * g;
#pragma unroll
      for (int nt = 0; nt < 4; ++nt) {
        u32x2 pq;
        pq.x = pk_bf16(acc[ot][nt][0] + bs[0], acc[ot][nt][1] + bs[1]);
        pq.y = pk_bf16(acc[ot][nt][2] + bs[2], acc[ot][nt][3] + bs[3]);
        *(u32x2*)(dst + (size_t)(b * NN + n0 + r + 16 * nt) * 32 + d0) = pq;
      }
    }
  }
}

// ---------------------------------------------------------------------------
// Kernel 2: per-column softmax statistics (round-1 verbatim, verified).
// ---------------------------------------------------------------------------
__global__ __launch_bounds__(256) void rowstat_kernel(
    const u16* __restrict__ qT, const u16* __restrict__ kT,
    float* __restrict__ Mx, float* __restrict__ invL) {
  const int lane = threadIdx.x & 63;
  const int wave = threadIdx.x >> 6;
  const int strip = blockIdx.x * 4 + wave;
  const int b  = strip >> 8;
  const int m0 = (strip & 255) * 16;
  const int r = lane & 15, g = lane >> 4;

  const u16x8 kB = *(const u16x8*)(kT + ((size_t)(b * NN + m0 + r)) * 32 + 8 * g);
  const u16* qbase = qT + ((size_t)(b * NN + r)) * 32 + 8 * g;

  float vmax = -3.0e38f, vsum = 0.f;
  for (int it = 0; it < 256; ++it) {
    const u16x8 qA = *(const u16x8*)(qbase + (size_t)it * 16 * 32);
    f32x4 s = mfma16(qA, kB, f32x4{0.f, 0.f, 0.f, 0.f});
    const float sm = fmaxf(fmaxf(s.x, s.y), fmaxf(s.z, s.w));
    const float nm = fmaxf(vmax, sm);
    vsum = vsum * exp2fast((vmax - nm) * L2E)
         + exp2fast((s.x - nm) * L2E) + exp2fast((s.y - nm) * L2E)
         + exp2fast((s.z - nm) * L2E) + exp2fast((s.w - nm) * L2E);
    vmax = nm;
  }
#pragma unroll
  for (int off = 16; off < 64; off <<= 1) {
    const float om = __shfl_xor(vmax, off);
    const float os = __shfl_xor(vsum, off);
    const float nm = fmaxf(vmax, om);
    vsum = vsum * exp2fast((vmax - nm) * L2E) + os * exp2fast((om - nm) * L2E);
    vmax = nm;
  }
  if (lane < 16) {
    Mx[b * NN + m0 + lane]   = vmax;
    invL[b * NN + m0 + lane] = 1.0f / vsum;
  }
}

// ---------------------------------------------------------------------------
// Kernel 3: attention — ROUND-1 VERBATIM (verified passing, absmax 0.0156).
// ---------------------------------------------------------------------------
__global__ __launch_bounds__(512, 2) void attn_kernel(
    const u16* __restrict__ qT, const u16* __restrict__ kT, const u16* __restrict__ vv,
    const float* __restrict__ Mx, const float* __restrict__ invL,
    const float* __restrict__ inp, const float* __restrict__ gptr,
    float* __restrict__ out) {
  __shared__ u32 q_lds[32 * 20];   // rows of 80B (16 data dwords + pad)
  __shared__ u32 v_lds[32 * 20];

  const int tid  = threadIdx.x;
  const int lane = tid & 63;
  const int wave = tid >> 6;                 // 0..7
  const int r = lane & 15, g = lane >> 4;

  const int bi   = blockIdx.x >> 5;          // 8 batches
  const int rest = blockIdx.x & 31;
  const int cs   = rest >> 2;                // 0..7  c-strip
  const int mg   = rest & 3;                 // 0..3  m-group
  const int m0   = (mg * 8 + wave) * 128;
  const int c0   = cs * 32;
  const float gamma = gptr[0];

  u16x8 kB[8];
#pragma unroll
  for (int t = 0; t < 8; ++t)
    kB[t] = *(const u16x8*)(kT + ((size_t)(bi * NN + m0 + t * 16 + r)) * DD + 8 * g);
  float msc[8];
#pragma unroll
  for (int t = 0; t < 8; ++t) msc[t] = Mx[bi * NN + m0 + t * 16 + r] * L2E;

  f32x4 acc[2][8];
#pragma unroll
  for (int cb = 0; cb < 2; ++cb)
#pragma unroll
    for (int t = 0; t < 8; ++t) acc[cb][t] = f32x4{0.f, 0.f, 0.f, 0.f};

  const int srow = tid >> 4;   // 0..31
  const int sdw  = tid & 15;   // dword within row
  const u32* qsrc = (const u32*)(qT + ((size_t)(bi * NN + srow)) * DD) + sdw;
  const u32* vsrc = (const u32*)(vv + ((size_t)(bi * CC + c0 + srow)) * NN) + sdw;
  u32* qdst = q_lds + srow * 20 + sdw;
  u32* vdst = v_lds + srow * 20 + sdw;

  qdst[0] = qsrc[0];
  vdst[0] = vsrc[0];

  for (int i0 = 0; i0 < NN; i0 += 32) {
    __syncthreads();                          // staged tile visible
    const bool more = (i0 + 32) < NN;
    u32 nq = 0, nv = 0;
    if (more) {
      nq = qsrc[(size_t)(i0 + 32) * (DD / 2)];
      nv = vsrc[(i0 + 32) >> 1];
    }

    const u16x8 qA0 = __builtin_bit_cast(u16x8, *(const u32x4*)(q_lds + r * 20 + 4 * g));
    const u16x8 qA1 = __builtin_bit_cast(u16x8, *(const u32x4*)(q_lds + (16 + r) * 20 + 4 * g));
    const u32x2 vl0 = *(const u32x2*)(v_lds + r * 20 + 2 * g);
    const u32x2 vh0 = *(const u32x2*)(v_lds + r * 20 + 2 * g + 8);
    const u32x2 vl1 = *(const u32x2*)(v_lds + (16 + r) * 20 + 2 * g);
    const u32x2 vh1 = *(const u32x2*)(v_lds + (16 + r) * 20 + 2 * g + 8);
    const u16x8 vA0 = __builtin_bit_cast(u16x8, u32x4{vl0.x, vl0.y, vh0.x, vh0.y});
    const u16x8 vA1 = __builtin_bit_cast(u16x8, u32x4{vl1.x, vl1.y, vh1.x, vh1.y});

#pragma unroll
    for (int t = 0; t < 8; ++t) {
      const f32x4 s0 = mfma16(qA0, kB[t], f32x4{0.f, 0.f, 0.f, 0.f});
      const f32x4 s1 = mfma16(qA1, kB[t], f32x4{0.f, 0.f, 0.f, 0.f});
      const float p0 = exp2fast(fmaf(s0.x, L2E, -msc[t]));
      const float p1 = exp2fast(fmaf(s0.y, L2E, -msc[t]));
      const float p2 = exp2fast(fmaf(s0.z, L2E, -msc[t]));
      const float p3 = exp2fast(fmaf(s0.w, L2E, -msc[t]));
      const float p4 = exp2fast(fmaf(s1.x, L2E, -msc[t]));
      const float p5 = exp2fast(fmaf(s1.y, L2E, -msc[t]));
      const float p6 = exp2fast(fmaf(s1.z, L2E, -msc[t]));
      const float p7 = exp2fast(fmaf(s1.w, L2E, -msc[t]));
      const u32x4 pb = {pk_bf16(p0, p1), pk_bf16(p2, p3), pk_bf16(p4, p5), pk_bf16(p6, p7)};
      const u16x8 PB = __builtin_bit_cast(u16x8, pb);
      acc[0][t] = mfma16(vA0, PB, acc[0][t]);
      acc[1][t] = mfma16(vA1, PB, acc[1][t]);
    }
    __syncthreads();                          // all reads done before overwrite
    if (more) { qdst[0] = nq; vdst[0] = nv; }
  }

#pragma unroll
  for (int t = 0; t < 8; ++t) {
    const float il = invL[bi * NN + m0 + t * 16 + r] * gamma;
#pragma unroll
    for (int cb = 0; cb < 2; ++cb) {
#pragma unroll
      for (int rr = 0; rr < 4; ++rr) {
        const int c = c0 + cb * 16 + g * 4 + rr;
        const size_t idx = ((size_t)(bi * CC + c)) * NN + m0 + t * 16 + r;
        out[idx] = acc[cb][t][rr] * il + inp[idx];
      }
    }
  }
}

// ---------------------------------------------------------------------------
// d_ws layout — EXACT round-1 (no Wb anywhere):
//   [0,2MB) qT | [2,4MB) kT | [4,20MB) vbf | [20MB,+128KB) Mx | [+128KB,+256KB) iL
// ---------------------------------------------------------------------------
extern "C" void kernel_launch(void* const* d_in, const int* in_sizes, int n_in,
                              void* d_out, int out_size, void* d_ws, size_t ws_size,
                              hipStream_t stream) {
  const float* in  = (const float*)d_in[0];
  const float* wq  = (const float*)d_in[1];
  const float* bq  = (const float*)d_in[2];
  const float* wk  = (const float*)d_in[3];
  const float* bk  = (const float*)d_in[4];
  const float* wv  = (const float*)d_in[5];
  const float* bv  = (const float*)d_in[6];
  const float* gam = (const float*)d_in[7];
  float* out = (float*)d_out;

  char* ws = (char*)d_ws;
  u16* qT   = (u16*)(ws);
  u16* kT   = (u16*)(ws + (2u << 20));
  u16* vbf  = (u16*)(ws + (4u << 20));
  float* Mx = (float*)(ws + (20u << 20));
  float* iL = (float*)(ws + (20u << 20) + (1u << 17));

  proj_kernel<<<512, 256, 0, stream>>>(in, wq, wk, wv, bq, bk, bv, qT, kT, vbf);
  rowstat_kernel<<<512, 256, 0, stream>>>(qT, kT, Mx, iL);
  attn_kernel<<<256, 512, 0, stream>>>(qT, kT, vbf, Mx, iL, in, gam, out);
}